// Round 2
// baseline (474.746 us; speedup 1.0000x reference)
//
#include <hip/hip_runtime.h>
#include <math.h>

#define Hn 80
#define Wn 80
#define HWn 6400

typedef unsigned short u16;
typedef __attribute__((ext_vector_type(8))) short s16x8;
typedef __attribute__((ext_vector_type(4))) float f32x4;

__device__ __forceinline__ float gelu_exact(float v) {
  return 0.5f * v * (1.f + erff(v * 0.70710678118654752f));
}
__device__ __forceinline__ u16 f2bf(float x) {
  unsigned u = __float_as_uint(x);
  return (u16)((u + 0x7fffu + ((u >> 16) & 1u)) >> 16);
}
typedef __attribute__((address_space(1))) const unsigned int* gptr_t;
typedef __attribute__((address_space(3))) unsigned int* lptr_t;
__device__ __forceinline__ void gld16(const void* g, void* l) {
  __builtin_amdgcn_global_load_lds((gptr_t)g, (lptr_t)l, 16, 0, 0);
}
__device__ __forceinline__ void ld16h(const u16* p, float* f) {
  uint4 a = *(const uint4*)p;
  uint4 c = *(const uint4*)(p + 8);
  unsigned w[8] = {a.x, a.y, a.z, a.w, c.x, c.y, c.z, c.w};
  #pragma unroll
  for (int j = 0; j < 8; ++j) {
    f[2 * j]     = __uint_as_float(w[j] << 16);
    f[2 * j + 1] = __uint_as_float(w[j] & 0xffff0000u);
  }
}

// ---------------- weight prep: fp32 -> bf16 (+ qkv gather, fc2 K-pad) ----------------
__global__ __launch_bounds__(256) void wprep_k(
    const float* __restrict__ q0w, const float* __restrict__ q0b,
    const float* __restrict__ q1w, const float* __restrict__ q1b,
    const float* __restrict__ projw, const float* __restrict__ f1w_1,
    const float* __restrict__ f2w_1, const float* __restrict__ pww,
    const float* __restrict__ f1w_2, const float* __restrict__ f2w_2,
    u16* Wq, float* Bq, u16* Wp, u16* Wf1a, u16* Wf2a, u16* Wpw, u16* Wf1b, u16* Wf2b) {
  int idx = blockIdx.x * 256 + threadIdx.x;
  if (idx < 49152) {
    int r = idx >> 7, ic = idx & 127;
    int sel = r >> 7, c = r & 127;
    const float* src = ((c >> 4) < 6 ? q0w : q1w);
    Wq[idx] = f2bf(src[(size_t)(sel * 128 + c) * 128 + ic]);
    return;
  }
  idx -= 49152;
  if (idx < 16384) { Wp[idx] = f2bf(projw[idx]); return; }
  idx -= 16384;
  if (idx < 24576) { Wf1a[idx] = f2bf(f1w_1[idx]); return; }
  idx -= 24576;
  if (idx < 16384) { int oc = idx >> 7, ic = idx & 127;
    Wf2a[idx] = ic < 96 ? f2bf(f2w_1[oc * 96 + ic]) : (u16)0; return; }
  idx -= 16384;
  if (idx < 16384) { Wpw[idx] = f2bf(pww[idx]); return; }
  idx -= 16384;
  if (idx < 24576) { Wf1b[idx] = f2bf(f1w_2[idx]); return; }
  idx -= 24576;
  if (idx < 16384) { int oc = idx >> 7, ic = idx & 127;
    Wf2b[idx] = ic < 96 ? f2bf(f2w_2[oc * 96 + ic]) : (u16)0; return; }
  idx -= 16384;
  if (idx < 384) {
    int sel = idx >> 7, c = idx & 127;
    Bq[idx] = ((c >> 4) < 6 ? q0b : q1b)[sel * 128 + c];
  }
}

// ---------------- LayerNorm: TMODE=1 -> bf16 [px][c]; TMODE=0 -> fp32 [c][px] ----------------
template<int TMODE>
__global__ __launch_bounds__(256) void ln_k(const float* __restrict__ in,
    const float* __restrict__ gw, const float* __restrict__ gb, void* __restrict__ outv) {
  __shared__ float sS[4][64];
  __shared__ float sQ[4][64];
  const int b = blockIdx.y;
  const int p0 = blockIdx.x * 64;
  const int px = threadIdx.x & 63;
  const int cg = threadIdx.x >> 6;
  const float* ip = in + (size_t)b * 128 * HWn + p0 + px;
  float s = 0.f, q = 0.f;
  #pragma unroll 8
  for (int c = cg * 32; c < cg * 32 + 32; ++c) { float v = ip[(size_t)c * HWn]; s += v; q += v * v; }
  sS[cg][px] = s; sQ[cg][px] = q;
  __syncthreads();
  float S = sS[0][px] + sS[1][px] + sS[2][px] + sS[3][px];
  float Q = sQ[0][px] + sQ[1][px] + sQ[2][px] + sQ[3][px];
  float mu = S * (1.f / 128.f);
  float rs = rsqrtf(Q * (1.f / 128.f) - mu * mu + 1e-6f);
  if (TMODE) {
    u16* op = (u16*)outv + ((size_t)b * HWn + p0 + px) * 128 + cg * 32;
    unsigned w[16];
    #pragma unroll
    for (int j = 0; j < 16; ++j) {
      int c0 = cg * 32 + 2 * j;
      float v0 = ip[(size_t)c0 * HWn];
      float v1 = ip[(size_t)(c0 + 1) * HWn];
      v0 = (v0 - mu) * rs * gw[c0] + gb[c0];
      v1 = (v1 - mu) * rs * gw[c0 + 1] + gb[c0 + 1];
      w[j] = (unsigned)f2bf(v0) | ((unsigned)f2bf(v1) << 16);
    }
    #pragma unroll
    for (int j = 0; j < 4; ++j)
      *(uint4*)(op + j * 8) = make_uint4(w[4 * j], w[4 * j + 1], w[4 * j + 2], w[4 * j + 3]);
  } else {
    float* op = (float*)outv + (size_t)b * 128 * HWn + p0 + px;
    #pragma unroll 8
    for (int c = cg * 32; c < cg * 32 + 32; ++c) {
      float v = ip[(size_t)c * HWn];
      op[(size_t)c * HWn] = (v - mu) * rs * gw[c] + gb[c];
    }
  }
}

// ---------------- bf16 MFMA GEMM: tile 128px x 64oc, K=128 staged whole ----------------
// X: bf16 [b][6400][128]; W: bf16 [OCT][128]
// ORIENT 0: D[oc][px] -> fp32 out [b][OCT][6400] (+bias, +resid optional)
// ORIENT 1: D[px][oc] -> bf16 out; SPLITQ: out [sel][b][px][128], else [b][px][OCT]
__device__ __forceinline__ s16x8 ldfrag(const u16* s, int row, int gk) {
  return *(const s16x8*)(s + row * 128 + ((gk ^ (row & 7)) << 3));
}

template<int ORIENT, int RES, int SPLITQ>
__global__ __launch_bounds__(256) void gemm_k(
    const u16* __restrict__ Xg, const u16* __restrict__ Wg,
    const float* __restrict__ bias, const float* __restrict__ resid,
    float* __restrict__ outF, u16* __restrict__ outH, int OCT) {
  __shared__ u16 sX[128 * 128];
  __shared__ u16 sW[64 * 128];
  const int tid = threadIdx.x, lane = tid & 63, wv = tid >> 6;
  const int b = blockIdx.y;
  const int px0 = blockIdx.x * 128;
  const int oc0 = blockIdx.z * 64;
  const u16* xb = Xg + ((size_t)b * HWn + px0) * 128;
  const u16* wb = Wg + (size_t)oc0 * 128;
  #pragma unroll
  for (int i = 0; i < 8; ++i) {
    int o16 = (wv * 8 + i) * 64 + lane;
    int r = o16 >> 4, g = o16 & 15;
    gld16(xb + (size_t)r * 128 + ((g ^ (r & 7)) << 3), (char*)sX + (size_t)(wv * 8 + i) * 1024);
  }
  #pragma unroll
  for (int i = 0; i < 4; ++i) {
    int o16 = (wv * 4 + i) * 64 + lane;
    int r = o16 >> 4, g = o16 & 15;
    gld16(wb + (size_t)r * 128 + ((g ^ (r & 7)) << 3), (char*)sW + (size_t)(wv * 4 + i) * 1024);
  }
  __syncthreads();
  const int l15 = lane & 15, l4 = lane >> 4;
  if (ORIENT == 0) {
    f32x4 acc[4][2] = {};
    #pragma unroll
    for (int ks = 0; ks < 4; ++ks) {
      int gk = ks * 4 + l4;
      s16x8 a[4], bb[2];
      #pragma unroll
      for (int mi = 0; mi < 4; ++mi) a[mi] = ldfrag(sW, mi * 16 + l15, gk);
      #pragma unroll
      for (int ni = 0; ni < 2; ++ni) bb[ni] = ldfrag(sX, wv * 32 + ni * 16 + l15, gk);
      #pragma unroll
      for (int mi = 0; mi < 4; ++mi)
        #pragma unroll
        for (int ni = 0; ni < 2; ++ni)
          acc[mi][ni] = __builtin_amdgcn_mfma_f32_16x16x32_bf16(a[mi], bb[ni], acc[mi][ni], 0, 0, 0);
    }
    #pragma unroll
    for (int mi = 0; mi < 4; ++mi) {
      #pragma unroll
      for (int rr = 0; rr < 4; ++rr) {
        int oc = oc0 + mi * 16 + l4 * 4 + rr;
        float bv = bias[oc];
        #pragma unroll
        for (int ni = 0; ni < 2; ++ni) {
          size_t idx = ((size_t)b * OCT + oc) * HWn + px0 + wv * 32 + ni * 16 + l15;
          float v = acc[mi][ni][rr] + bv;
          if (RES) v += resid[idx];
          outF[idx] = v;
        }
      }
    }
  } else {
    f32x4 acc[2][4] = {};
    #pragma unroll
    for (int ks = 0; ks < 4; ++ks) {
      int gk = ks * 4 + l4;
      s16x8 a[2], bb[4];
      #pragma unroll
      for (int mi = 0; mi < 2; ++mi) a[mi] = ldfrag(sX, wv * 32 + mi * 16 + l15, gk);
      #pragma unroll
      for (int ni = 0; ni < 4; ++ni) bb[ni] = ldfrag(sW, ni * 16 + l15, gk);
      #pragma unroll
      for (int mi = 0; mi < 2; ++mi)
        #pragma unroll
        for (int ni = 0; ni < 4; ++ni)
          acc[mi][ni] = __builtin_amdgcn_mfma_f32_16x16x32_bf16(a[mi], bb[ni], acc[mi][ni], 0, 0, 0);
    }
    #pragma unroll
    for (int ni = 0; ni < 4; ++ni) {
      int oc = oc0 + ni * 16 + l15;
      float bv = bias[oc];
      #pragma unroll
      for (int mi = 0; mi < 2; ++mi) {
        #pragma unroll
        for (int rr = 0; rr < 4; ++rr) {
          int px = px0 + wv * 32 + mi * 16 + l4 * 4 + rr;
          float v = acc[mi][ni][rr] + bv;
          u16 hv = f2bf(v);
          if (SPLITQ) {
            int sel = oc >> 7, c = oc & 127;
            outH[(((size_t)sel * 4 + b) * HWn + px) * 128 + c] = hv;
          } else {
            outH[((size_t)b * HWn + px) * (size_t)OCT + oc] = hv;
          }
        }
      }
    }
  }
}

// ---------------- neighborhood attention on bf16 [sel][b][px][128] ----------------
template<int KS, int DIL>
__device__ __forceinline__ void natt_body(const u16* __restrict__ qkv,
                                          u16* __restrict__ out, int b, int h, int p) {
  const int y = p / Wn, x = p - (p / Wn) * Wn;
  const u16* Qp = qkv + ((size_t)b * HWn + p) * 128 + h * 16;
  const u16* Kb = qkv + (size_t)(4 + b) * HWn * 128 + h * 16;
  const u16* Vb = qkv + (size_t)(8 + b) * HWn * 128 + h * 16;
  float qv[16];
  ld16h(Qp, qv);
  #pragma unroll
  for (int d = 0; d < 16; ++d) qv[d] *= 0.25f;
  constexpr int L = KS * KS;
  float lg[L];
  #pragma unroll
  for (int i = 0; i < KS; ++i) {
    #pragma unroll
    for (int j = 0; j < KS; ++j) {
      int yy = y + (i - KS / 2) * DIL;
      int xx = x + (j - KS / 2) * DIL;
      float a = 0.f;
      if (yy >= 0 && yy < Hn && xx >= 0 && xx < Wn) {
        float kv[16];
        ld16h(Kb + (size_t)(yy * Wn + xx) * 128, kv);
        #pragma unroll
        for (int d = 0; d < 16; ++d) a = fmaf(qv[d], kv[d], a);
      }
      lg[i * KS + j] = a;
    }
  }
  float mx = lg[0];
  #pragma unroll
  for (int l = 1; l < L; ++l) mx = fmaxf(mx, lg[l]);
  float sum = 0.f;
  #pragma unroll
  for (int l = 0; l < L; ++l) { float e = __expf(lg[l] - mx); lg[l] = e; sum += e; }
  float inv = 1.f / sum;
  float acc[16];
  #pragma unroll
  for (int d = 0; d < 16; ++d) acc[d] = 0.f;
  #pragma unroll
  for (int i = 0; i < KS; ++i) {
    #pragma unroll
    for (int j = 0; j < KS; ++j) {
      int yy = y + (i - KS / 2) * DIL;
      int xx = x + (j - KS / 2) * DIL;
      if (yy >= 0 && yy < Hn && xx >= 0 && xx < Wn) {
        float vv[16];
        ld16h(Vb + (size_t)(yy * Wn + xx) * 128, vv);
        float wl = lg[i * KS + j] * inv;
        #pragma unroll
        for (int d = 0; d < 16; ++d) acc[d] = fmaf(wl, vv[d], acc[d]);
      }
    }
  }
  unsigned wst[8];
  #pragma unroll
  for (int j = 0; j < 8; ++j)
    wst[j] = (unsigned)f2bf(acc[2 * j]) | ((unsigned)f2bf(acc[2 * j + 1]) << 16);
  u16* op = out + ((size_t)b * HWn + p) * 128 + h * 16;
  *(uint4*)op = make_uint4(wst[0], wst[1], wst[2], wst[3]);
  *(uint4*)(op + 8) = make_uint4(wst[4], wst[5], wst[6], wst[7]);
}

__global__ __launch_bounds__(256) void natt_k(const u16* __restrict__ qkv,
                                              u16* __restrict__ out) {
  const int b = blockIdx.y, h = blockIdx.z;
  const int p = blockIdx.x * 256 + threadIdx.x;
  if (h < 6) natt_body<3, 1>(qkv, out, b, h, p);
  else       natt_body<5, 2>(qkv, out, b, h, p);
}

// ---------------- msconvstar star: fp32 [c][px] in -> bf16 [px][128] out (96 real + pad0) ----------------
__device__ __forceinline__ float hh_val(const float* __restrict__ hb, int c, int p, int y, int x,
    const float* __restrict__ w0, const float* __restrict__ b0,
    const float* __restrict__ w1, const float* __restrict__ b1,
    const float* __restrict__ w2, const float* __restrict__ b2) {
  const float* hp = hb + (size_t)c * HWn;
  float center = hp[p];
  if (c < 64) {
    return center + fmaf(center, w0[c], b0[c]);
  } else if (c < 128) {
    int cc = c - 64;
    float acc = b1[cc];
    #pragma unroll
    for (int i = 0; i < 3; ++i)
      #pragma unroll
      for (int j = 0; j < 3; ++j) {
        int yy = y + i - 1, xx = x + j - 1;
        if (yy >= 0 && yy < Hn && xx >= 0 && xx < Wn)
          acc = fmaf(w1[cc * 9 + i * 3 + j], hp[yy * Wn + xx], acc);
      }
    return center + acc;
  } else {
    int cc = c - 128;
    float acc = b2[cc];
    #pragma unroll
    for (int i = 0; i < 5; ++i)
      #pragma unroll
      for (int j = 0; j < 5; ++j) {
        int yy = y + i - 2, xx = x + j - 2;
        if (yy >= 0 && yy < Hn && xx >= 0 && xx < Wn)
          acc = fmaf(w2[cc * 25 + i * 5 + j], hp[yy * Wn + xx], acc);
      }
    return center + acc;
  }
}

__global__ __launch_bounds__(256) void star_k(const float* __restrict__ hbuf,
    const float* __restrict__ w0, const float* __restrict__ b0,
    const float* __restrict__ w1, const float* __restrict__ b1,
    const float* __restrict__ w2, const float* __restrict__ b2,
    u16* __restrict__ g) {
  __shared__ u16 sG[64 * 136];
  const int b = blockIdx.y;
  const int px0 = blockIdx.x * 64;
  const int tid = threadIdx.x;
  const int px = tid >> 2, ct = tid & 3;
  const int p = px0 + px;
  const int y = p / Wn, x = p - (p / Wn) * Wn;
  const float* hb = hbuf + (size_t)b * 192 * HWn;
  #pragma unroll 1
  for (int i = 0; i < 24; ++i) {
    int c1 = i * 4 + ct;
    float h1 = hh_val(hb, c1, p, y, x, w0, b0, w1, b1, w2, b2);
    float h2 = hh_val(hb, c1 + 96, p, y, x, w0, b0, w1, b1, w2, b2);
    sG[px * 136 + c1] = f2bf(gelu_exact(h1) * h2);
  }
  #pragma unroll
  for (int j = 0; j < 8; ++j) sG[px * 136 + 96 + ct + j * 4] = 0;
  __syncthreads();
  u16* op = g + ((size_t)b * HWn + p) * 128 + ct * 32;
  const u16* sp = sG + px * 136 + ct * 32;
  #pragma unroll
  for (int j = 0; j < 4; ++j)
    *(uint4*)(op + j * 8) = *(const uint4*)(sp + j * 8);
}

// ---------------- cascaded sparse ----------------
__global__ __launch_bounds__(256) void dwg1_k(const float* __restrict__ in,
    const float* __restrict__ w, const float* __restrict__ bias, float* __restrict__ out) {
  const int b = blockIdx.y;
  const int c = blockIdx.z;
  const int p = blockIdx.x * 256 + threadIdx.x;
  const int y = p / Wn, x = p - (p / Wn) * Wn;
  const float* ip = in + ((size_t)b * 128 + c) * HWn;
  float acc = bias[c];
  #pragma unroll
  for (int i = 0; i < 3; ++i)
    #pragma unroll
    for (int j = 0; j < 3; ++j) {
      int yy = y + (i - 1), xx = x + (j - 1);
      if (yy >= 0 && yy < Hn && xx >= 0 && xx < Wn)
        acc = fmaf(w[c * 9 + i * 3 + j], ip[yy * Wn + xx], acc);
    }
  out[((size_t)b * 128 + c) * HWn + p] = gelu_exact(acc);
}

__global__ __launch_bounds__(256) void dwg2t_k(const float* __restrict__ in,
    const float* __restrict__ w, const float* __restrict__ bias, u16* __restrict__ out) {
  __shared__ u16 sG[64 * 136];
  const int b = blockIdx.y;
  const int px0 = blockIdx.x * 64;
  const int tid = threadIdx.x;
  const int px = tid >> 2, ct = tid & 3;
  const int p = px0 + px;
  const int y = p / Wn, x = p - (p / Wn) * Wn;
  const float* ib = in + (size_t)b * 128 * HWn;
  #pragma unroll 1
  for (int i = 0; i < 32; ++i) {
    int c = i * 4 + ct;
    const float* ip = ib + (size_t)c * HWn;
    float acc = bias[c];
    #pragma unroll
    for (int ii = 0; ii < 3; ++ii)
      #pragma unroll
      for (int jj = 0; jj < 3; ++jj) {
        int yy = y + (ii - 1) * 2, xx = x + (jj - 1) * 2;
        if (yy >= 0 && yy < Hn && xx >= 0 && xx < Wn)
          acc = fmaf(w[c * 9 + ii * 3 + jj], ip[yy * Wn + xx], acc);
      }
    sG[px * 136 + c] = f2bf(gelu_exact(acc));
  }
  __syncthreads();
  u16* op = out + ((size_t)b * HWn + p) * 128 + ct * 32;
  const u16* sp = sG + px * 136 + ct * 32;
  #pragma unroll
  for (int j = 0; j < 4; ++j)
    *(uint4*)(op + j * 8) = *(const uint4*)(sp + j * 8);
}

// ---------------- launch ----------------
extern "C" void kernel_launch(void* const* d_in, const int* in_sizes, int n_in,
                              void* d_out, int out_size, void* d_ws, size_t ws_size,
                              hipStream_t stream) {
  (void)in_sizes; (void)n_in; (void)out_size; (void)ws_size;
  const float* x      = (const float*)d_in[0];
  const float* n1w    = (const float*)d_in[1];
  const float* n1b    = (const float*)d_in[2];
  const float* n2w    = (const float*)d_in[3];
  const float* n2b    = (const float*)d_in[4];
  const float* n3w    = (const float*)d_in[5];
  const float* n3b    = (const float*)d_in[6];
  const float* n4w    = (const float*)d_in[7];
  const float* n4b    = (const float*)d_in[8];
  const float* qkv0w  = (const float*)d_in[9];
  const float* qkv0b  = (const float*)d_in[10];
  const float* qkv1w  = (const float*)d_in[11];
  const float* qkv1b  = (const float*)d_in[12];
  const float* projw  = (const float*)d_in[13];
  const float* projb  = (const float*)d_in[14];
  const float* m1fc1w = (const float*)d_in[15];
  const float* m1fc1b = (const float*)d_in[16];
  const float* m1dw0w = (const float*)d_in[17];
  const float* m1dw0b = (const float*)d_in[18];
  const float* m1dw1w = (const float*)d_in[19];
  const float* m1dw1b = (const float*)d_in[20];
  const float* m1dw2w = (const float*)d_in[21];
  const float* m1dw2b = (const float*)d_in[22];
  const float* m1fc2w = (const float*)d_in[23];
  const float* m1fc2b = (const float*)d_in[24];
  const float* smadw0w = (const float*)d_in[25];
  const float* smadw0b = (const float*)d_in[26];
  const float* smadw1w = (const float*)d_in[27];
  const float* smadw1b = (const float*)d_in[28];
  const float* smapww  = (const float*)d_in[29];
  const float* smapwb  = (const float*)d_in[30];
  const float* m2fc1w = (const float*)d_in[31];
  const float* m2fc1b = (const float*)d_in[32];
  const float* m2dw0w = (const float*)d_in[33];
  const float* m2dw0b = (const float*)d_in[34];
  const float* m2dw1w = (const float*)d_in[35];
  const float* m2dw1b = (const float*)d_in[36];
  const float* m2dw2w = (const float*)d_in[37];
  const float* m2dw2b = (const float*)d_in[38];
  const float* m2fc2w = (const float*)d_in[39];
  const float* m2fc2b = (const float*)d_in[40];

  float* out = (float*)d_out;
  char* wsb = (char*)d_ws;
  // region map (bytes):
  u16*  QKV = (u16*)(wsb + 0);           // 19,660,800 B  [sel][b][px][128]
  float* Hb = (float*)(wsb + 0);         // 19,660,800 B  [b][192][6400] (reuse)
  float* LNf = (float*)(wsb + 0);        // 13,107,200 B  (reuse)
  u16*  LNo = (u16*)(wsb + 19660800);    // 6,553,600 B   [b][px][128]
  u16*  ATT = (u16*)(wsb + 26214400);    // 6,553,600 B   (also G)
  float* T1 = (float*)(wsb + 19660800);  // 13,107,200 B  (overlaps LNo+ATT, block-3 only)
  u16*  T2  = (u16*)(wsb + 32768000);    // 6,553,600 B
  char* wp = wsb + 39321600;
  u16* Wq    = (u16*)wp;  wp += 98304;
  u16* Wproj = (u16*)wp;  wp += 32768;
  u16* Wf1a  = (u16*)wp;  wp += 49152;
  u16* Wf2a  = (u16*)wp;  wp += 32768;
  u16* Wpw   = (u16*)wp;  wp += 32768;
  u16* Wf1b  = (u16*)wp;  wp += 49152;
  u16* Wf2b  = (u16*)wp;  wp += 32768;
  float* Bq  = (float*)wp;

  dim3 blk(256);
  wprep_k<<<642, blk, 0, stream>>>(qkv0w, qkv0b, qkv1w, qkv1b, projw, m1fc1w, m1fc2w,
                                   smapww, m2fc1w, m2fc2w,
                                   Wq, Bq, Wproj, Wf1a, Wf2a, Wpw, Wf1b, Wf2b);

  // ---- Block 1: neighborhood attention ----
  ln_k<1><<<dim3(100, 4), blk, 0, stream>>>(x, n1w, n1b, LNo);
  gemm_k<1, 0, 1><<<dim3(50, 4, 6), blk, 0, stream>>>(LNo, Wq, Bq, nullptr, nullptr, QKV, 384);
  natt_k<<<dim3(25, 4, 8), blk, 0, stream>>>(QKV, ATT);
  gemm_k<0, 1, 0><<<dim3(50, 4, 2), blk, 0, stream>>>(ATT, Wproj, projb, x, out, nullptr, 128);

  // ---- Block 2: msconvstar (m1) ----
  ln_k<1><<<dim3(100, 4), blk, 0, stream>>>(out, n2w, n2b, LNo);
  gemm_k<0, 0, 0><<<dim3(50, 4, 3), blk, 0, stream>>>(LNo, Wf1a, m1fc1b, nullptr, Hb, nullptr, 192);
  star_k<<<dim3(100, 4), blk, 0, stream>>>(Hb, m1dw0w, m1dw0b, m1dw1w, m1dw1b, m1dw2w, m1dw2b, ATT);
  gemm_k<0, 1, 0><<<dim3(50, 4, 2), blk, 0, stream>>>(ATT, Wf2a, m1fc2b, out, out, nullptr, 128);

  // ---- Block 3: cascaded sparse ----
  ln_k<0><<<dim3(100, 4), blk, 0, stream>>>(out, n3w, n3b, LNf);
  dwg1_k<<<dim3(25, 4, 128), blk, 0, stream>>>(LNf, smadw0w, smadw0b, T1);
  dwg2t_k<<<dim3(100, 4), blk, 0, stream>>>(T1, smadw1w, smadw1b, T2);
  gemm_k<0, 1, 0><<<dim3(50, 4, 2), blk, 0, stream>>>(T2, Wpw, smapwb, out, out, nullptr, 128);

  // ---- Block 4: msconvstar (m2) ----
  ln_k<1><<<dim3(100, 4), blk, 0, stream>>>(out, n4w, n4b, LNo);
  gemm_k<0, 0, 0><<<dim3(50, 4, 3), blk, 0, stream>>>(LNo, Wf1b, m2fc1b, nullptr, Hb, nullptr, 192);
  star_k<<<dim3(100, 4), blk, 0, stream>>>(Hb, m2dw0w, m2dw0b, m2dw1w, m2dw1b, m2dw2w, m2dw2b, ATT);
  gemm_k<0, 1, 0><<<dim3(50, 4, 2), blk, 0, stream>>>(ATT, Wf2b, m2fc2b, out, out, nullptr, 128);
}